// Round 1
// baseline (295.288 us; speedup 1.0000x reference)
//
#include <hip/hip_runtime.h>
#include <math.h>

#define B_SZ   4
#define N_PTS  2048
#define EPSF   1e-6f

// ---- workspace float offsets ----
#define WS_ACC   0                      // [0] = feasibility ordered-pair overlap sum
#define WS_PSI   8                      // 8192 per-point |psi|
#define WS_KNN_R (WS_PSI + 8192)        // 4*6144 real knn dists
#define WS_KNN_F (WS_KNN_R + 24576)     // 4*6144 fake knn dists
#define WS_Q     (WS_KNN_F + 24576)     // quantile outputs
#define QZF (WS_Q + 0)
#define QZR (WS_Q + 7)
#define QXF (WS_Q + 14)
#define QXR (WS_Q + 19)
#define QYF (WS_Q + 24)
#define QYR (WS_Q + 29)
#define QDR (WS_Q + 34)   // 4 batches x 3
#define QDF (WS_Q + 46)   // 4 batches x 3

__constant__ float c_qs7[7] = {0.05f, 0.1f, 0.25f, 0.5f, 0.75f, 0.9f, 0.95f};
__constant__ float c_qs5[5] = {0.05f, 0.25f, 0.5f, 0.75f, 0.95f};
__constant__ float c_qs3[3] = {0.05f, 0.5f, 0.95f};

__device__ __forceinline__ void ins3(float& m0, float& m1, float& m2, float v) {
    if (v < m2) {
        m2 = v;
        if (m2 < m1) { float t = m1; m1 = m2; m2 = t; }
        if (m1 < m0) { float t = m0; m0 = m1; m1 = t; }
    }
}

__device__ __forceinline__ void ins4(float& m0, float& m1, float& m2, float& m3, float v) {
    if (v < m3) {
        m3 = v;
        if (m3 < m2) { float t = m2; m2 = m3; m3 = t; }
        if (m2 < m1) { float t = m1; m1 = m2; m2 = t; }
        if (m1 < m0) { float t = m0; m0 = m1; m1 = t; }
    }
}

// ---------------- init: zero accumulators ----------------
__global__ void hs_init_kernel(float* __restrict__ ws) {
    if (threadIdx.x < 8) ws[WS_ACC + threadIdx.x] = 0.f;
}

// ---------------- kNN (3 smallest incl. self-dist sqrt(EPS)) ----------------
// grid 4096 blocks x 256 threads; block -> 4 points (1 wave each)
__global__ __launch_bounds__(256) void hs_knn_kernel(const float* __restrict__ real,
                                                     const float* __restrict__ fake,
                                                     float* __restrict__ ws) {
    __shared__ float sx[N_PTS], sy[N_PTS];
    const int blk   = blockIdx.x;
    const int which = blk >> 11;          // 0 = real, 1 = fake
    const int rem   = blk & 2047;
    const int b     = rem >> 9;
    const int grp   = rem & 511;
    const int tid   = threadIdx.x;
    const float* src = (which ? fake : real) + (size_t)b * N_PTS * 3;
    for (int t = tid; t < N_PTS; t += 256) {
        sx[t] = src[t * 3 + 0];
        sy[t] = src[t * 3 + 1];
    }
    __syncthreads();
    const int wave = tid >> 6, lane = tid & 63;
    const int i = grp * 4 + wave;
    const float xi = sx[i], yi = sy[i];
    float m0 = INFINITY, m1 = INFINITY, m2 = INFINITY;
    for (int j = lane; j < N_PTS; j += 64) {
        float dx = xi - sx[j], dy = yi - sy[j];
        ins3(m0, m1, m2, sqrtf(dx * dx + dy * dy + EPSF));
    }
    for (int off = 1; off < 64; off <<= 1) {
        float b0 = __shfl_xor(m0, off);
        float b1 = __shfl_xor(m1, off);
        float b2 = __shfl_xor(m2, off);
        ins3(m0, m1, m2, b0);
        ins3(m0, m1, m2, b1);
        ins3(m0, m1, m2, b2);
    }
    if (lane == 0) {
        float* kout = ws + (which ? WS_KNN_F : WS_KNN_R) + b * (N_PTS * 3) + i * 3;
        kout[0] = m0; kout[1] = m1; kout[2] = m2;
    }
}

// ---------------- hexatic order |psi| per point (fake) ----------------
// grid 2048 blocks x 256 threads; block -> 4 points
__global__ __launch_bounds__(256) void hs_hex_kernel(const float* __restrict__ fake,
                                                     float* __restrict__ ws) {
    __shared__ float sx[N_PTS], sy[N_PTS];
    const int b   = blockIdx.x >> 9;
    const int grp = blockIdx.x & 511;
    const int tid = threadIdx.x;
    const float* src = fake + (size_t)b * N_PTS * 3;
    for (int t = tid; t < N_PTS; t += 256) {
        sx[t] = src[t * 3 + 0];
        sy[t] = src[t * 3 + 1];
    }
    __syncthreads();
    const int wave = tid >> 6, lane = tid & 63;
    const int i = grp * 4 + wave;
    const float xi = sx[i], yi = sy[i];

    // pass 1: 4th smallest dist (self excluded)
    float m0 = INFINITY, m1 = INFINITY, m2 = INFINITY, m3 = INFINITY;
    for (int j = lane; j < N_PTS; j += 64) {
        if (j == i) continue;
        float dx = xi - sx[j], dy = yi - sy[j];
        ins4(m0, m1, m2, m3, sqrtf(dx * dx + dy * dy + EPSF));
    }
    for (int off = 1; off < 64; off <<= 1) {
        float b0 = __shfl_xor(m0, off);
        float b1 = __shfl_xor(m1, off);
        float b2 = __shfl_xor(m2, off);
        float b3 = __shfl_xor(m3, off);
        ins4(m0, m1, m2, m3, b0);
        ins4(m0, m1, m2, m3, b1);
        ins4(m0, m1, m2, m3, b2);
        ins4(m0, m1, m2, m3, b3);
    }
    const float kth   = m3;
    const float sigma = fmaxf(0.1f * fmaxf(kth, EPSF), EPSF);
    const float inv_sigma = 1.f / sigma;

    // pass 2: weighted e^{i4theta} accumulation (incl. diagonal: dist=inf -> w=sigmoid(-50))
    float sw = 0.f, sre = 0.f, sim = 0.f;
    for (int j = lane; j < N_PTS; j += 64) {
        float dx = xi - sx[j], dy = yi - sy[j];
        float dist = (j == i) ? INFINITY : sqrtf(dx * dx + dy * dy + EPSF);
        float a = (fabsf(dx) < EPSF) ? (dx + EPSF) : dx;
        float arg = fminf(fmaxf((kth - dist) * inv_sigma, -50.f), 50.f);
        float w = 1.f / (1.f + __expf(-arg) * 0.f + expf(-arg));  // plain expf
        // e^{i4theta} = (a + i dy)^4 / (a^2+dy^2)^2
        float n2  = a * a + dy * dy;
        float z2r = a * a - dy * dy;
        float z2i = 2.f * a * dy;
        float z4r = z2r * z2r - z2i * z2i;
        float z4i = 2.f * z2r * z2i;
        float invn4 = 1.f / (n2 * n2);
        sw  += w;
        sre += w * z4r * invn4;
        sim += w * z4i * invn4;
    }
    for (int off = 1; off < 64; off <<= 1) {
        sw  += __shfl_xor(sw, off);
        sre += __shfl_xor(sre, off);
        sim += __shfl_xor(sim, off);
    }
    if (lane == 0) {
        float den = fmaxf(sw, EPSF);
        float pr = sre / den, pi = sim / den;
        ws[WS_PSI + b * N_PTS + i] = sqrtf(pr * pr + pi * pi);
    }
}

// ---------------- physical feasibility: ordered-pair overlap sum ----------------
// grid 2048 blocks x 256 threads; block -> 4 rows i
__global__ __launch_bounds__(256) void hs_feas_kernel(const float* __restrict__ fake,
                                                      float* __restrict__ ws) {
    __shared__ float sx[N_PTS], sy[N_PTS], sr[N_PTS];
    __shared__ float red[256];
    const int b   = blockIdx.x >> 9;
    const int grp = blockIdx.x & 511;
    const int tid = threadIdx.x;
    const float* src = fake + (size_t)b * N_PTS * 3;
    for (int t = tid; t < N_PTS; t += 256) {
        sx[t] = src[t * 3 + 0];
        sy[t] = src[t * 3 + 1];
        sr[t] = fabsf(src[t * 3 + 2]);
    }
    __syncthreads();
    const int wave = tid >> 6, lane = tid & 63;
    const int i = grp * 4 + wave;
    const float xi = sx[i], yi = sy[i], ri = sr[i];
    float acc = 0.f;
    for (int j = lane; j < N_PTS; j += 64) {
        if (j == i) continue;
        float dx = xi - sx[j], dy = yi - sy[j];
        float sq = dx * dx + dy * dy;
        if (sq > 0.f) {
            float ov = ri + sr[j] - (sqrtf(sq) + 1e-4f);
            acc += fmaxf(ov, 0.f);
        }
    }
    red[tid] = acc;
    __syncthreads();
    for (int s = 128; s > 0; s >>= 1) {
        if (tid < s) red[tid] += red[tid + s];
        __syncthreads();
    }
    if (tid == 0) atomicAdd(ws + WS_ACC, red[0]);
}

// ---------------- bitonic sort + quantiles ----------------
// 14 blocks x 1024 threads: aid 0..5 component arrays (n=8192), 6..13 knn arrays (n=6144, pad inf)
__global__ __launch_bounds__(1024) void hs_sortq_kernel(const float* __restrict__ real,
                                                        const float* __restrict__ fake,
                                                        float* __restrict__ ws) {
    __shared__ float s[8192];
    const int tid = threadIdx.x;
    const int aid = blockIdx.x;
    int n, nq, qoff;
    if (aid < 6) {
        const float* src = (aid & 1) ? real : fake;
        const int c = (aid < 2) ? 2 : ((aid < 4) ? 0 : 1);
        for (int t = tid; t < 8192; t += 1024) s[t] = src[t * 3 + c];
        n = 8192;
        nq = (aid < 2) ? 7 : 5;
        qoff = (aid == 0) ? QZF : (aid == 1) ? QZR : (aid == 2) ? QXF
             : (aid == 3) ? QXR : (aid == 4) ? QYF : QYR;
    } else {
        const int a = aid - 6;  // 0..3 real, 4..7 fake
        const float* kp = ws + ((a < 4) ? WS_KNN_R : WS_KNN_F) + (a & 3) * (N_PTS * 3);
        for (int t = tid; t < 8192; t += 1024) s[t] = (t < N_PTS * 3) ? kp[t] : INFINITY;
        n = N_PTS * 3;
        nq = 3;
        qoff = ((a < 4) ? QDR : QDF) + (a & 3) * 3;
    }
    __syncthreads();
    for (int k = 2; k <= 8192; k <<= 1) {
        for (int j = k >> 1; j > 0; j >>= 1) {
            for (int i = tid; i < 8192; i += 1024) {
                int ixj = i ^ j;
                if (ixj > i) {
                    float va = s[i], vb = s[ixj];
                    bool up = ((i & k) == 0);
                    bool sw = up ? (va > vb) : (va < vb);
                    if (sw) { s[i] = vb; s[ixj] = va; }
                }
            }
            __syncthreads();
        }
    }
    if (tid < nq) {
        const float* qs = (nq == 7) ? c_qs7 : (nq == 5) ? c_qs5 : c_qs3;
        float pos = qs[tid] * (float)(n - 1);
        int lo = (int)pos;
        float frac = pos - (float)lo;
        int hi = (lo + 1 > n - 1) ? (n - 1) : (lo + 1);
        ws[qoff + tid] = s[lo] + frac * (s[hi] - s[lo]);
    }
}

// ---------------- final combine ----------------
__global__ __launch_bounds__(256) void hs_final_kernel(const float* __restrict__ fake,
                                                       const float* __restrict__ fouts,
                                                       const float* __restrict__ ws,
                                                       float* __restrict__ out) {
    __shared__ float red[256];
    __shared__ float s_rsum;
    const int tid = threadIdx.x;
    float rs = 0.f, ps = 0.f;
    for (int t = tid; t < B_SZ * N_PTS; t += 256) {
        rs += fabsf(fake[t * 3 + 2]);
        ps += ws[WS_PSI + t];
    }
    red[tid] = rs;
    __syncthreads();
    for (int s = 128; s > 0; s >>= 1) {
        if (tid < s) red[tid] += red[tid + s];
        __syncthreads();
    }
    if (tid == 0) s_rsum = red[0];
    __syncthreads();
    red[tid] = ps;
    __syncthreads();
    for (int s = 128; s > 0; s >>= 1) {
        if (tid < s) red[tid] += red[tid + s];
        __syncthreads();
    }
    if (tid == 0) {
        float psi_sum = red[0];
        float loss = 0.f;
        // radius loss
        float sacc = 0.f;
        for (int q = 0; q < 7; ++q) { float d = ws[QZF + q] - ws[QZR + q]; sacc += d * d; }
        loss += sacc / 7.f;
        // physical feasibility: (ordered_sum/2) / (N * sum|r|)
        loss += (0.5f * ws[WS_ACC]) / ((float)N_PTS * s_rsum);
        // gan loss
        float g = 0.f;
        for (int b = 0; b < B_SZ; ++b) {
            float p = fouts[b];
            g += 0.9f * fmaxf(logf(p), -100.f) + 0.1f * fmaxf(logf(1.f - p), -100.f);
        }
        loss += -g / (float)B_SZ;
        // grid density loss
        float sx = 0.f, sy = 0.f;
        for (int q = 0; q < 5; ++q) {
            float dx = ws[QXF + q] - ws[QXR + q]; sx += dx * dx;
            float dy = ws[QYF + q] - ws[QYR + q]; sy += dy * dy;
        }
        loss += 0.5f * (sx / 5.f + sy / 5.f);
        // distance loss
        float sd = 0.f;
        for (int t = 0; t < 12; ++t) { float d = ws[QDF + t] - ws[QDR + t]; sd += d * d; }
        loss += sd / 12.f;
        // grid order loss
        loss += -psi_sum / (float)(B_SZ * N_PTS);
        out[0] = loss;
    }
}

extern "C" void kernel_launch(void* const* d_in, const int* in_sizes, int n_in,
                              void* d_out, int out_size, void* d_ws, size_t ws_size,
                              hipStream_t stream) {
    (void)in_sizes; (void)n_in; (void)out_size; (void)ws_size;
    const float* real  = (const float*)d_in[0];
    const float* fake  = (const float*)d_in[1];
    const float* fouts = (const float*)d_in[2];
    float* out = (float*)d_out;
    float* ws  = (float*)d_ws;

    hipLaunchKernelGGL(hs_init_kernel,  dim3(1),    dim3(64),   0, stream, ws);
    hipLaunchKernelGGL(hs_knn_kernel,   dim3(4096), dim3(256),  0, stream, real, fake, ws);
    hipLaunchKernelGGL(hs_hex_kernel,   dim3(2048), dim3(256),  0, stream, fake, ws);
    hipLaunchKernelGGL(hs_feas_kernel,  dim3(2048), dim3(256),  0, stream, fake, ws);
    hipLaunchKernelGGL(hs_sortq_kernel, dim3(14),   dim3(1024), 0, stream, real, fake, ws);
    hipLaunchKernelGGL(hs_final_kernel, dim3(1),    dim3(256),  0, stream, fake, fouts, ws, out);
}

// Round 2
// 209.616 us; speedup vs baseline: 1.4087x; 1.4087x over previous
//
#include <hip/hip_runtime.h>
#include <math.h>

#define B_SZ   4
#define N_PTS  2048
#define EPSF   1e-6f

// ---- workspace float offsets ----
#define WS_PSI   0                       // 8192 per-point |psi|
#define WS_KNN_R (WS_PSI + 8192)         // 4*6144 real knn dists
#define WS_KNN_F (WS_KNN_R + 24576)      // 4*6144 fake knn dists
#define WS_FEAS  (WS_KNN_F + 24576)      // 256 feasibility partials
#define WS_Q     (WS_FEAS + 256)         // 58 quantile outputs
#define QZF (WS_Q + 0)
#define QZR (WS_Q + 7)
#define QXF (WS_Q + 14)
#define QXR (WS_Q + 19)
#define QYF (WS_Q + 24)
#define QYR (WS_Q + 29)
#define QDR (WS_Q + 34)   // 4 batches x 3
#define QDF (WS_Q + 46)   // 4 batches x 3

__constant__ float c_qs7[7] = {0.05f, 0.1f, 0.25f, 0.5f, 0.75f, 0.9f, 0.95f};
__constant__ float c_qs5[5] = {0.05f, 0.25f, 0.5f, 0.75f, 0.95f};
__constant__ float c_qs3[3] = {0.05f, 0.5f, 0.95f};

__device__ __forceinline__ void ins3(float& m0, float& m1, float& m2, float v) {
    if (v < m2) {
        m2 = v;
        if (m2 < m1) { float t = m1; m1 = m2; m2 = t; }
        if (m1 < m0) { float t = m0; m0 = m1; m1 = t; }
    }
}

__device__ __forceinline__ void ins4(float& m0, float& m1, float& m2, float& m3, float v) {
    if (v < m3) {
        m3 = v;
        if (m3 < m2) { float t = m2; m2 = m3; m3 = t; }
        if (m2 < m1) { float t = m1; m1 = m2; m2 = t; }
        if (m1 < m0) { float t = m0; m0 = m1; m1 = t; }
    }
}

__device__ __forceinline__ unsigned int tokey(float f) {
    unsigned int u = __float_as_uint(f);
    return (u & 0x80000000u) ? ~u : (u | 0x80000000u);
}
__device__ __forceinline__ float fromkey(unsigned int k) {
    unsigned int u = (k & 0x80000000u) ? (k ^ 0x80000000u) : ~k;
    return __uint_as_float(u);
}

// ---------------- kNN (3 smallest incl. self-dist sqrt(EPS)) ----------------
// 8 clouds x 64 blocks; block=256thr, wave handles 8 points
__global__ __launch_bounds__(256) void hs_knn_kernel(const float* __restrict__ real,
                                                     const float* __restrict__ fake,
                                                     float* __restrict__ ws) {
    __shared__ float sx[N_PTS], sy[N_PTS];
    const int cloud = blockIdx.x >> 6;     // 0..7
    const int grp   = blockIdx.x & 63;
    const int which = cloud >> 2;          // 0 real, 1 fake
    const int b     = cloud & 3;
    const int tid   = threadIdx.x;
    const float* src = (which ? fake : real) + (size_t)b * N_PTS * 3;
    for (int t = tid; t < N_PTS; t += 256) {
        sx[t] = src[t * 3 + 0];
        sy[t] = src[t * 3 + 1];
    }
    __syncthreads();
    const int wave = tid >> 6, lane = tid & 63;
    const int p0 = grp * 32 + wave * 8;
    float px[8], py[8], m0[8], m1[8], m2[8];
#pragma unroll
    for (int t = 0; t < 8; ++t) {
        px[t] = sx[p0 + t]; py[t] = sy[p0 + t];
        m0[t] = m1[t] = m2[t] = INFINITY;
    }
    for (int j = lane; j < N_PTS; j += 64) {
        float bx = sx[j], by = sy[j];
#pragma unroll
        for (int t = 0; t < 8; ++t) {
            float dx = px[t] - bx, dy = py[t] - by;
            float d = sqrtf(fmaf(dx, dx, fmaf(dy, dy, EPSF)));
            ins3(m0[t], m1[t], m2[t], d);
        }
    }
#pragma unroll
    for (int off = 1; off < 64; off <<= 1) {
#pragma unroll
        for (int t = 0; t < 8; ++t) {
            float b0 = __shfl_xor(m0[t], off);
            float b1 = __shfl_xor(m1[t], off);
            float b2 = __shfl_xor(m2[t], off);
            ins3(m0[t], m1[t], m2[t], b0);
            ins3(m0[t], m1[t], m2[t], b1);
            ins3(m0[t], m1[t], m2[t], b2);
        }
    }
    if (lane == 0) {
        float* kout = ws + (which ? WS_KNN_F : WS_KNN_R) + b * (N_PTS * 3);
#pragma unroll
        for (int t = 0; t < 8; ++t) {
            const int i = p0 + t;
            kout[i * 3 + 0] = m0[t];
            kout[i * 3 + 1] = m1[t];
            kout[i * 3 + 2] = m2[t];
        }
    }
}

// ---------------- hexatic order |psi| per point (fake) ----------------
// 4 clouds x 128 blocks; wave handles 4 points
__global__ __launch_bounds__(256) void hs_hex_kernel(const float* __restrict__ fake,
                                                     float* __restrict__ ws) {
    __shared__ float sx[N_PTS], sy[N_PTS];
    const int b   = blockIdx.x >> 7;
    const int grp = blockIdx.x & 127;
    const int tid = threadIdx.x;
    const float* src = fake + (size_t)b * N_PTS * 3;
    for (int t = tid; t < N_PTS; t += 256) {
        sx[t] = src[t * 3 + 0];
        sy[t] = src[t * 3 + 1];
    }
    __syncthreads();
    const int wave = tid >> 6, lane = tid & 63;
    const int p0 = grp * 16 + wave * 4;
    float px[4], py[4], m0[4], m1[4], m2[4], m3[4];
#pragma unroll
    for (int t = 0; t < 4; ++t) {
        px[t] = sx[p0 + t]; py[t] = sy[p0 + t];
        m0[t] = m1[t] = m2[t] = m3[t] = INFINITY;
    }
    // pass 1: 4th smallest (self excluded via d=inf)
    for (int j = lane; j < N_PTS; j += 64) {
        float bx = sx[j], by = sy[j];
#pragma unroll
        for (int t = 0; t < 4; ++t) {
            float dx = px[t] - bx, dy = py[t] - by;
            float d = sqrtf(fmaf(dx, dx, fmaf(dy, dy, EPSF)));
            d = (j == p0 + t) ? INFINITY : d;
            ins4(m0[t], m1[t], m2[t], m3[t], d);
        }
    }
#pragma unroll
    for (int off = 1; off < 64; off <<= 1) {
#pragma unroll
        for (int t = 0; t < 4; ++t) {
            float b0 = __shfl_xor(m0[t], off);
            float b1 = __shfl_xor(m1[t], off);
            float b2 = __shfl_xor(m2[t], off);
            float b3 = __shfl_xor(m3[t], off);
            ins4(m0[t], m1[t], m2[t], m3[t], b0);
            ins4(m0[t], m1[t], m2[t], m3[t], b1);
            ins4(m0[t], m1[t], m2[t], m3[t], b2);
            ins4(m0[t], m1[t], m2[t], m3[t], b3);
        }
    }
    float kth[4], inv_sigma[4];
#pragma unroll
    for (int t = 0; t < 4; ++t) {
        kth[t] = m3[t];
        inv_sigma[t] = 1.f / fmaxf(0.1f * fmaxf(kth[t], EPSF), EPSF);
    }
    // pass 2: weighted e^{i4theta}
    float sw[4], sre[4], sim[4];
#pragma unroll
    for (int t = 0; t < 4; ++t) { sw[t] = 0.f; sre[t] = 0.f; sim[t] = 0.f; }
    for (int j = lane; j < N_PTS; j += 64) {
        float bx = sx[j], by = sy[j];
#pragma unroll
        for (int t = 0; t < 4; ++t) {
            float dx = px[t] - bx, dy = py[t] - by;
            float dist = sqrtf(fmaf(dx, dx, fmaf(dy, dy, EPSF)));
            dist = (j == p0 + t) ? INFINITY : dist;
            float a = (fabsf(dx) < EPSF) ? (dx + EPSF) : dx;
            float arg = fminf(fmaxf((kth[t] - dist) * inv_sigma[t], -50.f), 50.f);
            float w = __builtin_amdgcn_rcpf(1.f + __expf(-arg));
            float aa = a * a, bb = dy * dy;
            float n2  = aa + bb;
            float z2r = aa - bb;
            float z2i = 2.f * a * dy;
            float z4r = fmaf(z2r, z2r, -(z2i * z2i));
            float z4i = 2.f * z2r * z2i;
            float winv = w * __builtin_amdgcn_rcpf(n2 * n2);
            sw[t] += w;
            sre[t] = fmaf(winv, z4r, sre[t]);
            sim[t] = fmaf(winv, z4i, sim[t]);
        }
    }
#pragma unroll
    for (int off = 1; off < 64; off <<= 1) {
#pragma unroll
        for (int t = 0; t < 4; ++t) {
            sw[t]  += __shfl_xor(sw[t], off);
            sre[t] += __shfl_xor(sre[t], off);
            sim[t] += __shfl_xor(sim[t], off);
        }
    }
    if (lane == 0) {
#pragma unroll
        for (int t = 0; t < 4; ++t) {
            float den = fmaxf(sw[t], EPSF);
            float pr = sre[t] / den, pi = sim[t] / den;
            ws[WS_PSI + b * N_PTS + p0 + t] = sqrtf(fmaf(pr, pr, pi * pi));
        }
    }
}

// ---------------- physical feasibility: per-block partial of ordered-pair overlaps ----
// 4 clouds x 64 blocks; wave handles 8 points
__global__ __launch_bounds__(256) void hs_feas_kernel(const float* __restrict__ fake,
                                                      float* __restrict__ ws) {
    __shared__ float sx[N_PTS], sy[N_PTS], sr[N_PTS];
    __shared__ float red[256];
    const int b   = blockIdx.x >> 6;
    const int grp = blockIdx.x & 63;
    const int tid = threadIdx.x;
    const float* src = fake + (size_t)b * N_PTS * 3;
    for (int t = tid; t < N_PTS; t += 256) {
        sx[t] = src[t * 3 + 0];
        sy[t] = src[t * 3 + 1];
        sr[t] = fabsf(src[t * 3 + 2]);
    }
    __syncthreads();
    const int wave = tid >> 6, lane = tid & 63;
    const int p0 = grp * 32 + wave * 8;
    float px[8], py[8], pr[8];
#pragma unroll
    for (int t = 0; t < 8; ++t) { px[t] = sx[p0 + t]; py[t] = sy[p0 + t]; pr[t] = sr[p0 + t]; }
    float acc = 0.f;
    for (int j = lane; j < N_PTS; j += 64) {
        float bx = sx[j], by = sy[j], br = sr[j];
#pragma unroll
        for (int t = 0; t < 8; ++t) {
            float dx = px[t] - bx, dy = py[t] - by;
            float sq = fmaf(dx, dx, dy * dy);
            float ov = pr[t] + br - (sqrtf(sq) + 1e-4f);
            acc += (sq > 0.f) ? fmaxf(ov, 0.f) : 0.f;
        }
    }
    red[tid] = acc;
    __syncthreads();
    for (int s = 128; s > 0; s >>= 1) {
        if (tid < s) red[tid] += red[tid + s];
        __syncthreads();
    }
    if (tid == 0) ws[WS_FEAS + blockIdx.x] = red[0];
}

// ---------------- exact quantile selection: 58 blocks, 1 per (array, q) ----------------
__global__ __launch_bounds__(256) void hs_select_kernel(const float* __restrict__ real,
                                                        const float* __restrict__ fake,
                                                        float* __restrict__ ws) {
    __shared__ unsigned int s_part[4];
    __shared__ unsigned int s_min[4];
    const int tid = threadIdx.x, wave = tid >> 6, lane = tid & 63;
    const int jb = blockIdx.x;

    const float* src; int step, n, slot; float q;
    if (jb < 34) {
        int aid, qi;
        if (jb < 7)       { aid = 0; qi = jb; }
        else if (jb < 14) { aid = 1; qi = jb - 7; }
        else              { aid = 2 + (jb - 14) / 5; qi = (jb - 14) % 5; }
        const float* base = (aid & 1) ? real : fake;
        const int c = (aid < 2) ? 2 : ((aid < 4) ? 0 : 1);
        src = base + c; step = 3; n = 8192;
        q = (aid < 2) ? c_qs7[qi] : c_qs5[qi];
        slot = ((aid == 0) ? QZF : (aid == 1) ? QZR : (aid == 2) ? QXF
              : (aid == 3) ? QXR : (aid == 4) ? QYF : QYR) + qi;
    } else {
        const int a = jb - 34;            // 0..23
        const int side = a / 12;          // 0 real, 1 fake
        const int b = (a % 12) / 3, qi = a % 3;
        src = ws + (side ? WS_KNN_F : WS_KNN_R) + b * (N_PTS * 3);
        step = 1; n = N_PTS * 3;
        q = c_qs3[qi];
        slot = (side ? QDF : QDR) + b * 3 + qi;
    }

    unsigned int r[32];
#pragma unroll
    for (int u = 0; u < 32; ++u) {
        int e = u * 256 + tid;
        r[u] = (e < n) ? tokey(src[(size_t)e * step]) : 0xFFFFFFFFu;
    }

    const float pos = q * (float)(n - 1);
    const int k = (int)pos;
    const float frac = pos - (float)k;

    unsigned int lo = 0u, hi = 0xFFFFFFFFu;
    while (lo < hi) {
        unsigned int mid = lo + ((hi - lo) >> 1);
        unsigned int c = 0;
#pragma unroll
        for (int u = 0; u < 32; ++u) c += (r[u] <= mid) ? 1u : 0u;
#pragma unroll
        for (int off = 1; off < 64; off <<= 1) c += (unsigned int)__shfl_xor((int)c, off);
        if (lane == 0) s_part[wave] = c;
        __syncthreads();
        unsigned int tot = s_part[0] + s_part[1] + s_part[2] + s_part[3];
        __syncthreads();
        if (tot >= (unsigned int)(k + 1)) hi = mid; else lo = mid + 1;
    }
    const unsigned int vk = lo;

    // count_le(vk) and min of keys > vk (for the k+1-th order stat, tie-safe)
    unsigned int c = 0, mg = 0xFFFFFFFFu;
#pragma unroll
    for (int u = 0; u < 32; ++u) {
        c += (r[u] <= vk) ? 1u : 0u;
        if (r[u] > vk && r[u] < mg) mg = r[u];
    }
#pragma unroll
    for (int off = 1; off < 64; off <<= 1) {
        c += (unsigned int)__shfl_xor((int)c, off);
        unsigned int om = (unsigned int)__shfl_xor((int)mg, off);
        mg = (om < mg) ? om : mg;
    }
    if (lane == 0) { s_part[wave] = c; s_min[wave] = mg; }
    __syncthreads();
    if (tid == 0) {
        unsigned int tot = s_part[0] + s_part[1] + s_part[2] + s_part[3];
        unsigned int mga = s_min[0];
        if (s_min[1] < mga) mga = s_min[1];
        if (s_min[2] < mga) mga = s_min[2];
        if (s_min[3] < mga) mga = s_min[3];
        unsigned int vhi = (tot >= (unsigned int)(k + 2)) ? vk : mga;
        float flo = fromkey(vk), fhi = fromkey(vhi);
        ws[slot] = flo + frac * (fhi - flo);
    }
}

// ---------------- final combine ----------------
__global__ __launch_bounds__(256) void hs_final_kernel(const float* __restrict__ fake,
                                                       const float* __restrict__ fouts,
                                                       const float* __restrict__ ws,
                                                       float* __restrict__ out) {
    __shared__ float red[256];
    __shared__ float s_rsum, s_psum;
    const int tid = threadIdx.x;
    float rs = 0.f, ps = 0.f;
    for (int t = tid; t < B_SZ * N_PTS; t += 256) {
        rs += fabsf(fake[t * 3 + 2]);
        ps += ws[WS_PSI + t];
    }
    float fs = ws[WS_FEAS + tid];

    red[tid] = rs;
    __syncthreads();
    for (int s = 128; s > 0; s >>= 1) {
        if (tid < s) red[tid] += red[tid + s];
        __syncthreads();
    }
    if (tid == 0) s_rsum = red[0];
    __syncthreads();
    red[tid] = ps;
    __syncthreads();
    for (int s = 128; s > 0; s >>= 1) {
        if (tid < s) red[tid] += red[tid + s];
        __syncthreads();
    }
    if (tid == 0) s_psum = red[0];
    __syncthreads();
    red[tid] = fs;
    __syncthreads();
    for (int s = 128; s > 0; s >>= 1) {
        if (tid < s) red[tid] += red[tid + s];
        __syncthreads();
    }
    if (tid == 0) {
        float feas_sum = red[0];
        float loss = 0.f;
        // radius loss
        float sacc = 0.f;
        for (int q = 0; q < 7; ++q) { float d = ws[QZF + q] - ws[QZR + q]; sacc += d * d; }
        loss += sacc / 7.f;
        // physical feasibility: (ordered_sum/2) / (N * sum|r|)
        loss += (0.5f * feas_sum) / ((float)N_PTS * s_rsum);
        // gan loss
        float g = 0.f;
        for (int b = 0; b < B_SZ; ++b) {
            float p = fouts[b];
            g += 0.9f * fmaxf(logf(p), -100.f) + 0.1f * fmaxf(logf(1.f - p), -100.f);
        }
        loss += -g / (float)B_SZ;
        // grid density loss
        float sx = 0.f, sy = 0.f;
        for (int q = 0; q < 5; ++q) {
            float dx = ws[QXF + q] - ws[QXR + q]; sx += dx * dx;
            float dy = ws[QYF + q] - ws[QYR + q]; sy += dy * dy;
        }
        loss += 0.5f * (sx / 5.f + sy / 5.f);
        // distance loss
        float sd = 0.f;
        for (int t = 0; t < 12; ++t) { float d = ws[QDF + t] - ws[QDR + t]; sd += d * d; }
        loss += sd / 12.f;
        // grid order loss
        loss += -s_psum / (float)(B_SZ * N_PTS);
        out[0] = loss;
    }
}

extern "C" void kernel_launch(void* const* d_in, const int* in_sizes, int n_in,
                              void* d_out, int out_size, void* d_ws, size_t ws_size,
                              hipStream_t stream) {
    (void)in_sizes; (void)n_in; (void)out_size; (void)ws_size;
    const float* real  = (const float*)d_in[0];
    const float* fake  = (const float*)d_in[1];
    const float* fouts = (const float*)d_in[2];
    float* out = (float*)d_out;
    float* ws  = (float*)d_ws;

    hipLaunchKernelGGL(hs_knn_kernel,    dim3(512), dim3(256), 0, stream, real, fake, ws);
    hipLaunchKernelGGL(hs_hex_kernel,    dim3(512), dim3(256), 0, stream, fake, ws);
    hipLaunchKernelGGL(hs_feas_kernel,   dim3(256), dim3(256), 0, stream, fake, ws);
    hipLaunchKernelGGL(hs_select_kernel, dim3(58),  dim3(256), 0, stream, real, fake, ws);
    hipLaunchKernelGGL(hs_final_kernel,  dim3(1),   dim3(256), 0, stream, fake, fouts, ws, out);
}

// Round 3
// 130.651 us; speedup vs baseline: 2.2601x; 1.6044x over previous
//
#include <hip/hip_runtime.h>
#include <math.h>

#define B_SZ   4
#define N_PTS  2048
#define EPSF   1e-6f

// ---- workspace float offsets ----
#define WS_KNN_R 0                       // 4*6144 real knn dists
#define WS_KNN_F 24576                   // 4*6144 fake knn dists
#define WS_FEAS  49152                   // 512 feasibility partials (fake blocks)
#define WS_PSIP  49664                   // 512 psi partials (fake blocks)
#define WS_RSUM  50176                   // 4 per-batch sum|r| (fake)
#define WS_Q     50180                   // 58 quantile outputs
#define QZF (WS_Q + 0)
#define QZR (WS_Q + 7)
#define QXF (WS_Q + 14)
#define QXR (WS_Q + 19)
#define QYF (WS_Q + 24)
#define QYR (WS_Q + 29)
#define QDR (WS_Q + 34)   // 4 batches x 3
#define QDF (WS_Q + 46)   // 4 batches x 3

__constant__ float c_qs7[7] = {0.05f, 0.1f, 0.25f, 0.5f, 0.75f, 0.9f, 0.95f};
__constant__ float c_qs5[5] = {0.05f, 0.25f, 0.5f, 0.75f, 0.95f};
__constant__ float c_qs3[3] = {0.05f, 0.5f, 0.95f};

#define CE(a, b) { float _lo = fminf(a, b), _hi = fmaxf(a, b); a = _lo; b = _hi; }

// branchless sorted-insert (ascending)
__device__ __forceinline__ void ins3a(float m[3], float v) {
    float h0 = fmaxf(m[0], v); m[0] = fminf(m[0], v);
    float h1 = fmaxf(m[1], h0); m[1] = fminf(m[1], h0);
    m[2] = fminf(m[2], h1);
}
__device__ __forceinline__ void ins5a(float m[5], float v) {
    float h0 = fmaxf(m[0], v); m[0] = fminf(m[0], v);
    float h1 = fmaxf(m[1], h0); m[1] = fminf(m[1], h0);
    float h2 = fmaxf(m[2], h1); m[2] = fminf(m[2], h1);
    float h3 = fmaxf(m[3], h2); m[3] = fminf(m[3], h2);
    m[4] = fminf(m[4], h3);
}

__device__ __forceinline__ unsigned int tokey(float f) {
    unsigned int u = __float_as_uint(f);
    return (u & 0x80000000u) ? ~u : (u | 0x80000000u);
}
__device__ __forceinline__ float fromkey(unsigned int k) {
    unsigned int u = (k & 0x80000000u) ? (k ^ 0x80000000u) : ~k;
    return __uint_as_float(u);
}

// ---------------- fused pair kernel ----------------
// blocks 0..511 : fake clouds — knn + feasibility + hexatic (4 pts/wave)
// blocks 512..767: real clouds — knn only (8 pts/wave)
__global__ __launch_bounds__(256) void hs_pair_kernel(const float* __restrict__ real,
                                                      const float* __restrict__ fake,
                                                      float* __restrict__ ws) {
    __shared__ float2 sxy[N_PTS];
    __shared__ float sr[N_PTS];
    __shared__ float red[256];
    const int tid = threadIdx.x, wave = tid >> 6, lane = tid & 63;
    const int blk = blockIdx.x;

    if (blk < 512) {
        // ---------- fake fused path ----------
        const int b = blk >> 7, grp = blk & 127;
        const float* src = fake + (size_t)b * N_PTS * 3;
        for (int t = tid; t < N_PTS; t += 256) {
            const float* p = src + t * 3;
            sxy[t] = make_float2(p[0], p[1]);
            sr[t]  = fabsf(p[2]);
        }
        __syncthreads();
        const int p0 = grp * 16 + wave * 4;
        float px[4], py[4], pri[4], m[4][5];
#pragma unroll
        for (int t = 0; t < 4; ++t) {
            px[t] = sxy[p0 + t].x; py[t] = sxy[p0 + t].y;
            pri[t] = sr[p0 + t] - 1e-4f;
            m[t][0] = m[t][1] = m[t][2] = m[t][3] = m[t][4] = INFINITY;
        }
        // pass 1: squared-dist top-5 (incl self sq=0) + feasibility overlap
        float acc = 0.f;
        for (int j = lane; j < N_PTS; j += 64) {
            float2 q = sxy[j]; float br = sr[j];
#pragma unroll
            for (int t = 0; t < 4; ++t) {
                float dx = px[t] - q.x, dy = py[t] - q.y;
                float sq = fmaf(dx, dx, dy * dy);
                ins5a(m[t], sq);
                float ov = fmaxf((pri[t] + br) - sqrtf(sq), 0.f);
                acc += (sq > 0.f) ? ov : 0.f;
            }
        }
        // butterfly merge of sorted-5 lists: bitonic lower-half + 5-sort network
#pragma unroll
        for (int off = 1; off < 64; off <<= 1) {
#pragma unroll
            for (int t = 0; t < 4; ++t) {
                float b0 = __shfl_xor(m[t][0], off);
                float b1 = __shfl_xor(m[t][1], off);
                float b2 = __shfl_xor(m[t][2], off);
                float b3 = __shfl_xor(m[t][3], off);
                float b4 = __shfl_xor(m[t][4], off);
                float l0 = fminf(m[t][0], b4);
                float l1 = fminf(m[t][1], b3);
                float l2 = fminf(m[t][2], b2);
                float l3 = fminf(m[t][3], b1);
                float l4 = fminf(m[t][4], b0);
                CE(l0, l3); CE(l1, l4); CE(l0, l2); CE(l1, l3);
                CE(l0, l1); CE(l2, l4); CE(l1, l2); CE(l3, l4); CE(l2, l3);
                m[t][0] = l0; m[t][1] = l1; m[t][2] = l2; m[t][3] = l3; m[t][4] = l4;
            }
        }
        // knn output (3 smallest incl self) + hex kth (4th smallest excl self)
        if (lane == 0) {
            float* kout = ws + WS_KNN_F + b * (N_PTS * 3);
#pragma unroll
            for (int t = 0; t < 4; ++t) {
                const int i = p0 + t;
                kout[i * 3 + 0] = sqrtf(m[t][0] + EPSF);
                kout[i * 3 + 1] = sqrtf(m[t][1] + EPSF);
                kout[i * 3 + 2] = sqrtf(m[t][2] + EPSF);
            }
        }
        float kth[4], invs[4];
#pragma unroll
        for (int t = 0; t < 4; ++t) {
            kth[t] = sqrtf(m[t][4] + EPSF);
            invs[t] = 1.f / fmaxf(0.1f * fmaxf(kth[t], EPSF), EPSF);
        }
        // pass 2: weighted e^{i4theta}
        float sw[4], sre[4], sim[4];
#pragma unroll
        for (int t = 0; t < 4; ++t) { sw[t] = 0.f; sre[t] = 0.f; sim[t] = 0.f; }
        for (int j = lane; j < N_PTS; j += 64) {
            float2 q = sxy[j];
#pragma unroll
            for (int t = 0; t < 4; ++t) {
                float dx = px[t] - q.x, dy = py[t] - q.y;
                float sq = fmaf(dx, dx, dy * dy);
                float dist = sqrtf(sq + EPSF);
                dist = (j == p0 + t) ? INFINITY : dist;
                float a = dx + ((fabsf(dx) < EPSF) ? EPSF : 0.f);
                float arg = fminf(fmaxf((kth[t] - dist) * invs[t], -50.f), 50.f);
                float e = __expf(-arg);
                float w = __builtin_amdgcn_rcpf(1.f + e);
                float aa = a * a, bb = dy * dy;
                float n2 = aa + bb;
                float z2r = aa - bb;
                float t0 = a * dy; float z2i = t0 + t0;
                float inv = __builtin_amdgcn_rcpf(n2);
                float ur = z2r * inv, ui = z2i * inv;
                float e4r = fmaf(ur, ur, -(ui * ui));
                float t1 = ur * ui; float e4i = t1 + t1;
                sw[t] += w;
                sre[t] = fmaf(w, e4r, sre[t]);
                sim[t] = fmaf(w, e4i, sim[t]);
            }
        }
#pragma unroll
        for (int off = 1; off < 64; off <<= 1) {
#pragma unroll
            for (int t = 0; t < 4; ++t) {
                sw[t]  += __shfl_xor(sw[t], off);
                sre[t] += __shfl_xor(sre[t], off);
                sim[t] += __shfl_xor(sim[t], off);
            }
        }
        float mypsi = 0.f;
        if (lane == 0) {
#pragma unroll
            for (int t = 0; t < 4; ++t) {
                float den = fmaxf(sw[t], EPSF);
                float pr = sre[t] / den, pi = sim[t] / den;
                mypsi += sqrtf(fmaf(pr, pr, pi * pi));
            }
        }
        // block reductions: feasibility partial, psi partial, (grp0) r-sum
        red[tid] = acc;
        __syncthreads();
        for (int s = 128; s > 0; s >>= 1) {
            if (tid < s) red[tid] += red[tid + s];
            __syncthreads();
        }
        if (tid == 0) ws[WS_FEAS + blk] = red[0];
        __syncthreads();
        red[tid] = (lane == 0) ? mypsi : 0.f;
        __syncthreads();
        for (int s = 128; s > 0; s >>= 1) {
            if (tid < s) red[tid] += red[tid + s];
            __syncthreads();
        }
        if (tid == 0) ws[WS_PSIP + blk] = red[0];
        if (grp == 0) {
            __syncthreads();
            float rs = 0.f;
            for (int t = tid; t < N_PTS; t += 256) rs += sr[t];
            red[tid] = rs;
            __syncthreads();
            for (int s = 128; s > 0; s >>= 1) {
                if (tid < s) red[tid] += red[tid + s];
                __syncthreads();
            }
            if (tid == 0) ws[WS_RSUM + b] = red[0];
        }
    } else {
        // ---------- real knn path ----------
        const int rb = blk - 512;
        const int b = rb >> 6, grp = rb & 63;
        const float* src = real + (size_t)b * N_PTS * 3;
        for (int t = tid; t < N_PTS; t += 256) {
            const float* p = src + t * 3;
            sxy[t] = make_float2(p[0], p[1]);
        }
        __syncthreads();
        const int p0 = grp * 32 + wave * 8;
        float px[8], py[8], m[8][3];
#pragma unroll
        for (int t = 0; t < 8; ++t) {
            px[t] = sxy[p0 + t].x; py[t] = sxy[p0 + t].y;
            m[t][0] = m[t][1] = m[t][2] = INFINITY;
        }
        for (int j = lane; j < N_PTS; j += 64) {
            float2 q = sxy[j];
#pragma unroll
            for (int t = 0; t < 8; ++t) {
                float dx = px[t] - q.x, dy = py[t] - q.y;
                float sq = fmaf(dx, dx, dy * dy);
                ins3a(m[t], sq);
            }
        }
#pragma unroll
        for (int off = 1; off < 64; off <<= 1) {
#pragma unroll
            for (int t = 0; t < 8; ++t) {
                float b0 = __shfl_xor(m[t][0], off);
                float b1 = __shfl_xor(m[t][1], off);
                float b2 = __shfl_xor(m[t][2], off);
                float l0 = fminf(m[t][0], b2);
                float l1 = fminf(m[t][1], b1);
                float l2 = fminf(m[t][2], b0);
                CE(l0, l1); CE(l0, l2); CE(l1, l2);
                m[t][0] = l0; m[t][1] = l1; m[t][2] = l2;
            }
        }
        if (lane == 0) {
            float* kout = ws + WS_KNN_R + b * (N_PTS * 3);
#pragma unroll
            for (int t = 0; t < 8; ++t) {
                const int i = p0 + t;
                kout[i * 3 + 0] = sqrtf(m[t][0] + EPSF);
                kout[i * 3 + 1] = sqrtf(m[t][1] + EPSF);
                kout[i * 3 + 2] = sqrtf(m[t][2] + EPSF);
            }
        }
    }
}

// ---------------- exact quantile selection: 58 blocks, 1 per (array, q) ----------------
__global__ __launch_bounds__(256) void hs_select_kernel(const float* __restrict__ real,
                                                        const float* __restrict__ fake,
                                                        float* __restrict__ ws) {
    __shared__ unsigned int s_part[4];
    __shared__ unsigned int s_min[4];
    const int tid = threadIdx.x, wave = tid >> 6, lane = tid & 63;
    const int jb = blockIdx.x;

    const float* src; int step, n, slot; float q;
    if (jb < 34) {
        int aid, qi;
        if (jb < 7)       { aid = 0; qi = jb; }
        else if (jb < 14) { aid = 1; qi = jb - 7; }
        else              { aid = 2 + (jb - 14) / 5; qi = (jb - 14) % 5; }
        const float* base = (aid & 1) ? real : fake;
        const int c = (aid < 2) ? 2 : ((aid < 4) ? 0 : 1);
        src = base + c; step = 3; n = 8192;
        q = (aid < 2) ? c_qs7[qi] : c_qs5[qi];
        slot = ((aid == 0) ? QZF : (aid == 1) ? QZR : (aid == 2) ? QXF
              : (aid == 3) ? QXR : (aid == 4) ? QYF : QYR) + qi;
    } else {
        const int a = jb - 34;            // 0..23
        const int side = a / 12;          // 0 real, 1 fake
        const int b = (a % 12) / 3, qi = a % 3;
        src = ws + (side ? WS_KNN_F : WS_KNN_R) + b * (N_PTS * 3);
        step = 1; n = N_PTS * 3;
        q = c_qs3[qi];
        slot = (side ? QDF : QDR) + b * 3 + qi;
    }

    unsigned int r[32];
#pragma unroll
    for (int u = 0; u < 32; ++u) {
        int e = u * 256 + tid;
        r[u] = (e < n) ? tokey(src[(size_t)e * step]) : 0xFFFFFFFFu;
    }

    const float pos = q * (float)(n - 1);
    const int k = (int)pos;
    const float frac = pos - (float)k;

    unsigned int lo = 0u, hi = 0xFFFFFFFFu;
    while (lo < hi) {
        unsigned int mid = lo + ((hi - lo) >> 1);
        unsigned int c = 0;
#pragma unroll
        for (int u = 0; u < 32; ++u) c += (r[u] <= mid) ? 1u : 0u;
#pragma unroll
        for (int off = 1; off < 64; off <<= 1) c += (unsigned int)__shfl_xor((int)c, off);
        if (lane == 0) s_part[wave] = c;
        __syncthreads();
        unsigned int tot = s_part[0] + s_part[1] + s_part[2] + s_part[3];
        __syncthreads();
        if (tot >= (unsigned int)(k + 1)) hi = mid; else lo = mid + 1;
    }
    const unsigned int vk = lo;

    unsigned int c = 0, mg = 0xFFFFFFFFu;
#pragma unroll
    for (int u = 0; u < 32; ++u) {
        c += (r[u] <= vk) ? 1u : 0u;
        if (r[u] > vk && r[u] < mg) mg = r[u];
    }
#pragma unroll
    for (int off = 1; off < 64; off <<= 1) {
        c += (unsigned int)__shfl_xor((int)c, off);
        unsigned int om = (unsigned int)__shfl_xor((int)mg, off);
        mg = (om < mg) ? om : mg;
    }
    if (lane == 0) { s_part[wave] = c; s_min[wave] = mg; }
    __syncthreads();
    if (tid == 0) {
        unsigned int tot = s_part[0] + s_part[1] + s_part[2] + s_part[3];
        unsigned int mga = s_min[0];
        if (s_min[1] < mga) mga = s_min[1];
        if (s_min[2] < mga) mga = s_min[2];
        if (s_min[3] < mga) mga = s_min[3];
        unsigned int vhi = (tot >= (unsigned int)(k + 2)) ? vk : mga;
        float flo = fromkey(vk), fhi = fromkey(vhi);
        ws[slot] = flo + frac * (fhi - flo);
    }
}

// ---------------- final combine ----------------
__global__ __launch_bounds__(256) void hs_final_kernel(const float* __restrict__ fouts,
                                                       const float* __restrict__ ws,
                                                       float* __restrict__ out) {
    __shared__ float red[256];
    __shared__ float s_feas;
    const int tid = threadIdx.x;
    float fs = 0.f, ps = 0.f;
    for (int t = tid; t < 512; t += 256) {
        fs += ws[WS_FEAS + t];
        ps += ws[WS_PSIP + t];
    }
    red[tid] = fs;
    __syncthreads();
    for (int s = 128; s > 0; s >>= 1) {
        if (tid < s) red[tid] += red[tid + s];
        __syncthreads();
    }
    if (tid == 0) s_feas = red[0];
    __syncthreads();
    red[tid] = ps;
    __syncthreads();
    for (int s = 128; s > 0; s >>= 1) {
        if (tid < s) red[tid] += red[tid + s];
        __syncthreads();
    }
    if (tid == 0) {
        float psi_sum = red[0];
        float rsum = ws[WS_RSUM + 0] + ws[WS_RSUM + 1] + ws[WS_RSUM + 2] + ws[WS_RSUM + 3];
        float loss = 0.f;
        // radius loss
        float sacc = 0.f;
        for (int q = 0; q < 7; ++q) { float d = ws[QZF + q] - ws[QZR + q]; sacc += d * d; }
        loss += sacc / 7.f;
        // physical feasibility: (ordered_sum/2) / (N * sum|r|)
        loss += (0.5f * s_feas) / ((float)N_PTS * rsum);
        // gan loss
        float g = 0.f;
        for (int b = 0; b < B_SZ; ++b) {
            float p = fouts[b];
            g += 0.9f * fmaxf(logf(p), -100.f) + 0.1f * fmaxf(logf(1.f - p), -100.f);
        }
        loss += -g / (float)B_SZ;
        // grid density loss
        float sx = 0.f, sy = 0.f;
        for (int q = 0; q < 5; ++q) {
            float dx = ws[QXF + q] - ws[QXR + q]; sx += dx * dx;
            float dy = ws[QYF + q] - ws[QYR + q]; sy += dy * dy;
        }
        loss += 0.5f * (sx / 5.f + sy / 5.f);
        // distance loss
        float sd = 0.f;
        for (int t = 0; t < 12; ++t) { float d = ws[QDF + t] - ws[QDR + t]; sd += d * d; }
        loss += sd / 12.f;
        // grid order loss
        loss += -psi_sum / (float)(B_SZ * N_PTS);
        out[0] = loss;
    }
}

extern "C" void kernel_launch(void* const* d_in, const int* in_sizes, int n_in,
                              void* d_out, int out_size, void* d_ws, size_t ws_size,
                              hipStream_t stream) {
    (void)in_sizes; (void)n_in; (void)out_size; (void)ws_size;
    const float* real  = (const float*)d_in[0];
    const float* fake  = (const float*)d_in[1];
    const float* fouts = (const float*)d_in[2];
    float* out = (float*)d_out;
    float* ws  = (float*)d_ws;

    hipLaunchKernelGGL(hs_pair_kernel,   dim3(768), dim3(256), 0, stream, real, fake, ws);
    hipLaunchKernelGGL(hs_select_kernel, dim3(58),  dim3(256), 0, stream, real, fake, ws);
    hipLaunchKernelGGL(hs_final_kernel,  dim3(1),   dim3(256), 0, stream, fouts, ws, out);
}

// Round 4
// 121.604 us; speedup vs baseline: 2.4283x; 1.0744x over previous
//
#include <hip/hip_runtime.h>
#include <math.h>

#define B_SZ   4
#define N_PTS  2048
#define EPSF   1e-6f

// ---- workspace float offsets ----
#define WS_KNN_R 0                       // 4*6144 real knn dists
#define WS_KNN_F 24576                   // 4*6144 fake knn dists
#define WS_FEAS  49152                   // 1024 feasibility partials (fake blocks)
#define WS_PSIP  50176                   // 1024 psi partials (fake blocks)
#define WS_RSUM  51200                   // 4 per-batch sum|r| (fake)
#define WS_Q     51204                   // 58 quantile outputs
#define QZF (WS_Q + 0)
#define QZR (WS_Q + 7)
#define QXF (WS_Q + 14)
#define QXR (WS_Q + 19)
#define QYF (WS_Q + 24)
#define QYR (WS_Q + 29)
#define QDR (WS_Q + 34)   // 4 batches x 3
#define QDF (WS_Q + 46)   // 4 batches x 3

__constant__ float c_qs7[7] = {0.05f, 0.1f, 0.25f, 0.5f, 0.75f, 0.9f, 0.95f};
__constant__ float c_qs5[5] = {0.05f, 0.25f, 0.5f, 0.75f, 0.95f};
__constant__ float c_qs3[3] = {0.05f, 0.5f, 0.95f};

#define CE(a, b) { float _lo = fminf(a, b), _hi = fmaxf(a, b); a = _lo; b = _hi; }

// branchless sorted-insert (ascending)
__device__ __forceinline__ void ins3a(float m[3], float v) {
    float h0 = fmaxf(m[0], v); m[0] = fminf(m[0], v);
    float h1 = fmaxf(m[1], h0); m[1] = fminf(m[1], h0);
    m[2] = fminf(m[2], h1);
}
__device__ __forceinline__ void ins5a(float m[5], float v) {
    float h0 = fmaxf(m[0], v); m[0] = fminf(m[0], v);
    float h1 = fmaxf(m[1], h0); m[1] = fminf(m[1], h0);
    float h2 = fmaxf(m[2], h1); m[2] = fminf(m[2], h1);
    float h3 = fmaxf(m[3], h2); m[3] = fminf(m[3], h2);
    m[4] = fminf(m[4], h3);
}

__device__ __forceinline__ unsigned int tokey(float f) {
    unsigned int u = __float_as_uint(f);
    return (u & 0x80000000u) ? ~u : (u | 0x80000000u);
}
__device__ __forceinline__ float fromkey(unsigned int k) {
    unsigned int u = (k & 0x80000000u) ? (k ^ 0x80000000u) : ~k;
    return __uint_as_float(u);
}

// ---------------- fused pair kernel ----------------
// blocks 0..1023  : fake clouds — knn + feasibility + hexatic (2 pts/wave)
// blocks 1024..1535: real clouds — knn only (4 pts/wave)
__global__ __launch_bounds__(256) void hs_pair_kernel(const float* __restrict__ real,
                                                      const float* __restrict__ fake,
                                                      float* __restrict__ ws) {
    __shared__ float2 sxy[N_PTS];
    __shared__ float sr[N_PTS];
    __shared__ float red[256];
    const int tid = threadIdx.x, wave = tid >> 6, lane = tid & 63;
    const int blk = blockIdx.x;

    if (blk < 1024) {
        // ---------- fake fused path (2 targets/wave) ----------
        const int b = blk >> 8, grp = blk & 255;
        const float* src = fake + (size_t)b * N_PTS * 3;
        for (int t = tid; t < N_PTS; t += 256) {
            const float* p = src + t * 3;
            sxy[t] = make_float2(p[0], p[1]);
            sr[t]  = fabsf(p[2]);
        }
        __syncthreads();
        const int p0 = grp * 8 + wave * 2;
        float px[2], py[2], pri[2], m[2][5];
#pragma unroll
        for (int t = 0; t < 2; ++t) {
            px[t] = sxy[p0 + t].x; py[t] = sxy[p0 + t].y;
            pri[t] = sr[p0 + t] - 1e-4f;
            m[t][0] = m[t][1] = m[t][2] = m[t][3] = m[t][4] = INFINITY;
        }
        // pass 1: squared-dist top-5 (incl self sq=0) + feasibility overlap
        float acc = 0.f;
        for (int j = lane; j < N_PTS; j += 64) {
            float2 q = sxy[j]; float br = sr[j];
#pragma unroll
            for (int t = 0; t < 2; ++t) {
                float dx = px[t] - q.x, dy = py[t] - q.y;
                float sq = fmaf(dx, dx, dy * dy);
                ins5a(m[t], sq);
                float ov = fmaxf((pri[t] + br) - sqrtf(sq), 0.f);
                acc += (sq > 0.f) ? ov : 0.f;
            }
        }
        // butterfly merge of sorted-5 lists
#pragma unroll
        for (int off = 1; off < 64; off <<= 1) {
#pragma unroll
            for (int t = 0; t < 2; ++t) {
                float b0 = __shfl_xor(m[t][0], off);
                float b1 = __shfl_xor(m[t][1], off);
                float b2 = __shfl_xor(m[t][2], off);
                float b3 = __shfl_xor(m[t][3], off);
                float b4 = __shfl_xor(m[t][4], off);
                float l0 = fminf(m[t][0], b4);
                float l1 = fminf(m[t][1], b3);
                float l2 = fminf(m[t][2], b2);
                float l3 = fminf(m[t][3], b1);
                float l4 = fminf(m[t][4], b0);
                CE(l0, l3); CE(l1, l4); CE(l0, l2); CE(l1, l3);
                CE(l0, l1); CE(l2, l4); CE(l1, l2); CE(l3, l4); CE(l2, l3);
                m[t][0] = l0; m[t][1] = l1; m[t][2] = l2; m[t][3] = l3; m[t][4] = l4;
            }
        }
        if (lane == 0) {
            float* kout = ws + WS_KNN_F + b * (N_PTS * 3);
#pragma unroll
            for (int t = 0; t < 2; ++t) {
                const int i = p0 + t;
                kout[i * 3 + 0] = sqrtf(m[t][0] + EPSF);
                kout[i * 3 + 1] = sqrtf(m[t][1] + EPSF);
                kout[i * 3 + 2] = sqrtf(m[t][2] + EPSF);
            }
        }
        float kth[2], invs[2];
#pragma unroll
        for (int t = 0; t < 2; ++t) {
            kth[t] = sqrtf(m[t][4] + EPSF);
            invs[t] = 1.f / fmaxf(0.1f * fmaxf(kth[t], EPSF), EPSF);
        }
        // pass 2: weighted e^{i4theta}
        float sw[2], sre[2], sim[2];
#pragma unroll
        for (int t = 0; t < 2; ++t) { sw[t] = 0.f; sre[t] = 0.f; sim[t] = 0.f; }
        for (int j = lane; j < N_PTS; j += 64) {
            float2 q = sxy[j];
#pragma unroll
            for (int t = 0; t < 2; ++t) {
                float dx = px[t] - q.x, dy = py[t] - q.y;
                float sq = fmaf(dx, dx, dy * dy);
                float dist = sqrtf(sq + EPSF);
                dist = (j == p0 + t) ? INFINITY : dist;
                float a = dx + ((fabsf(dx) < EPSF) ? EPSF : 0.f);
                float arg = fminf(fmaxf((kth[t] - dist) * invs[t], -50.f), 50.f);
                float e = __expf(-arg);
                float w = __builtin_amdgcn_rcpf(1.f + e);
                float aa = a * a, bb = dy * dy;
                float n2 = aa + bb;
                float z2r = aa - bb;
                float t0 = a * dy; float z2i = t0 + t0;
                float inv = __builtin_amdgcn_rcpf(n2);
                float ur = z2r * inv, ui = z2i * inv;
                float e4r = fmaf(ur, ur, -(ui * ui));
                float t1 = ur * ui; float e4i = t1 + t1;
                sw[t] += w;
                sre[t] = fmaf(w, e4r, sre[t]);
                sim[t] = fmaf(w, e4i, sim[t]);
            }
        }
#pragma unroll
        for (int off = 1; off < 64; off <<= 1) {
#pragma unroll
            for (int t = 0; t < 2; ++t) {
                sw[t]  += __shfl_xor(sw[t], off);
                sre[t] += __shfl_xor(sre[t], off);
                sim[t] += __shfl_xor(sim[t], off);
            }
        }
        float mypsi = 0.f;
        if (lane == 0) {
#pragma unroll
            for (int t = 0; t < 2; ++t) {
                float den = fmaxf(sw[t], EPSF);
                float pr = sre[t] / den, pi = sim[t] / den;
                mypsi += sqrtf(fmaf(pr, pr, pi * pi));
            }
        }
        // block reductions
        red[tid] = acc;
        __syncthreads();
        for (int s = 128; s > 0; s >>= 1) {
            if (tid < s) red[tid] += red[tid + s];
            __syncthreads();
        }
        if (tid == 0) ws[WS_FEAS + blk] = red[0];
        __syncthreads();
        red[tid] = (lane == 0) ? mypsi : 0.f;
        __syncthreads();
        for (int s = 128; s > 0; s >>= 1) {
            if (tid < s) red[tid] += red[tid + s];
            __syncthreads();
        }
        if (tid == 0) ws[WS_PSIP + blk] = red[0];
        if (grp == 0) {
            __syncthreads();
            float rs = 0.f;
            for (int t = tid; t < N_PTS; t += 256) rs += sr[t];
            red[tid] = rs;
            __syncthreads();
            for (int s = 128; s > 0; s >>= 1) {
                if (tid < s) red[tid] += red[tid + s];
                __syncthreads();
            }
            if (tid == 0) ws[WS_RSUM + b] = red[0];
        }
    } else {
        // ---------- real knn path (4 targets/wave) ----------
        const int rb = blk - 1024;
        const int b = rb >> 7, grp = rb & 127;
        const float* src = real + (size_t)b * N_PTS * 3;
        for (int t = tid; t < N_PTS; t += 256) {
            const float* p = src + t * 3;
            sxy[t] = make_float2(p[0], p[1]);
        }
        __syncthreads();
        const int p0 = grp * 16 + wave * 4;
        float px[4], py[4], m[4][3];
#pragma unroll
        for (int t = 0; t < 4; ++t) {
            px[t] = sxy[p0 + t].x; py[t] = sxy[p0 + t].y;
            m[t][0] = m[t][1] = m[t][2] = INFINITY;
        }
        for (int j = lane; j < N_PTS; j += 64) {
            float2 q = sxy[j];
#pragma unroll
            for (int t = 0; t < 4; ++t) {
                float dx = px[t] - q.x, dy = py[t] - q.y;
                float sq = fmaf(dx, dx, dy * dy);
                ins3a(m[t], sq);
            }
        }
#pragma unroll
        for (int off = 1; off < 64; off <<= 1) {
#pragma unroll
            for (int t = 0; t < 4; ++t) {
                float b0 = __shfl_xor(m[t][0], off);
                float b1 = __shfl_xor(m[t][1], off);
                float b2 = __shfl_xor(m[t][2], off);
                float l0 = fminf(m[t][0], b2);
                float l1 = fminf(m[t][1], b1);
                float l2 = fminf(m[t][2], b0);
                CE(l0, l1); CE(l0, l2); CE(l1, l2);
                m[t][0] = l0; m[t][1] = l1; m[t][2] = l2;
            }
        }
        if (lane == 0) {
            float* kout = ws + WS_KNN_R + b * (N_PTS * 3);
#pragma unroll
            for (int t = 0; t < 4; ++t) {
                const int i = p0 + t;
                kout[i * 3 + 0] = sqrtf(m[t][0] + EPSF);
                kout[i * 3 + 1] = sqrtf(m[t][1] + EPSF);
                kout[i * 3 + 2] = sqrtf(m[t][2] + EPSF);
            }
        }
    }
}

// ---------------- exact quantile via 3-pass histogram radix select ----------------
// 58 blocks, 1 per (array, q). Passes over key bits [31:21], [20:10], [9:0].
__global__ __launch_bounds__(256) void hs_select_kernel(const float* __restrict__ real,
                                                        const float* __restrict__ fake,
                                                        float* __restrict__ ws) {
    __shared__ unsigned int hist[2048];
    __shared__ unsigned int wtot[4];
    __shared__ unsigned int s_bin, s_rank;
    __shared__ unsigned int s_part[4], s_min[4];
    const int tid = threadIdx.x, wave = tid >> 6, lane = tid & 63;
    const int jb = blockIdx.x;

    const float* src; int step, n, slot; float q;
    if (jb < 34) {
        int aid, qi;
        if (jb < 7)       { aid = 0; qi = jb; }
        else if (jb < 14) { aid = 1; qi = jb - 7; }
        else              { aid = 2 + (jb - 14) / 5; qi = (jb - 14) % 5; }
        const float* base = (aid & 1) ? real : fake;
        const int c = (aid < 2) ? 2 : ((aid < 4) ? 0 : 1);
        src = base + c; step = 3; n = 8192;
        q = (aid < 2) ? c_qs7[qi] : c_qs5[qi];
        slot = ((aid == 0) ? QZF : (aid == 1) ? QZR : (aid == 2) ? QXF
              : (aid == 3) ? QXR : (aid == 4) ? QYF : QYR) + qi;
    } else {
        const int a = jb - 34;            // 0..23
        const int side = a / 12;          // 0 real, 1 fake
        const int b = (a % 12) / 3, qi = a % 3;
        src = ws + (side ? WS_KNN_F : WS_KNN_R) + b * (N_PTS * 3);
        step = 1; n = N_PTS * 3;
        q = c_qs3[qi];
        slot = (side ? QDF : QDR) + b * 3 + qi;
    }

    unsigned int r[32];
#pragma unroll
    for (int u = 0; u < 32; ++u) {
        int e = u * 256 + tid;
        r[u] = (e < n) ? tokey(src[(size_t)e * step]) : 0xFFFFFFFFu;
    }

    const float pos = q * (float)(n - 1);
    const int k = (int)pos;
    const float frac = pos - (float)k;

    unsigned int prefix = 0;
    unsigned int kk = (unsigned int)k;
#pragma unroll
    for (int pass = 0; pass < 3; ++pass) {
        const int shift = (pass == 0) ? 21 : (pass == 1) ? 10 : 0;
        // zero hist
        for (int i = tid; i < 2048; i += 256) hist[i] = 0u;
        __syncthreads();
        // build
#pragma unroll
        for (int u = 0; u < 32; ++u) {
            unsigned int key = r[u];
            bool act = (pass == 0) ? true
                     : (pass == 1) ? ((key >> 21) == (prefix >> 21))
                                   : ((key >> 10) == (prefix >> 10));
            if (act) atomicAdd(&hist[(key >> shift) & 2047u], 1u);
        }
        __syncthreads();
        // scan 2048 bins: 8 per thread + wave scan + cross-wave offsets
        unsigned int c[8], psum = 0;
        const int base = tid * 8;
#pragma unroll
        for (int i = 0; i < 8; ++i) { c[i] = hist[base + i]; psum += c[i]; }
        unsigned int v = psum;
#pragma unroll
        for (int off = 1; off < 64; off <<= 1) {
            unsigned int nb = (unsigned int)__shfl_up((int)v, off);
            if (lane >= off) v += nb;
        }
        if (lane == 63) wtot[wave] = v;
        __syncthreads();
        unsigned int woff = 0;
        for (int w2 = 0; w2 < wave; ++w2) woff += wtot[w2];
        unsigned int incl = v + woff;
        unsigned int excl = incl - psum;
        if (excl <= kk && kk < incl) {
            unsigned int cum = excl;
#pragma unroll
            for (int i = 0; i < 8; ++i) {
                if (kk < cum + c[i]) { s_bin = (unsigned int)(base + i); s_rank = kk - cum; break; }
                cum += c[i];
            }
        }
        __syncthreads();
        prefix |= s_bin << shift;
        kk = s_rank;
        __syncthreads();
    }
    const unsigned int vk = prefix;

    // count_le(vk) and min of keys > vk (tie-safe k+1-th order stat)
    unsigned int cle = 0, mg = 0xFFFFFFFFu;
#pragma unroll
    for (int u = 0; u < 32; ++u) {
        cle += (r[u] <= vk) ? 1u : 0u;
        if (r[u] > vk && r[u] < mg) mg = r[u];
    }
#pragma unroll
    for (int off = 1; off < 64; off <<= 1) {
        cle += (unsigned int)__shfl_xor((int)cle, off);
        unsigned int om = (unsigned int)__shfl_xor((int)mg, off);
        mg = (om < mg) ? om : mg;
    }
    if (lane == 0) { s_part[wave] = cle; s_min[wave] = mg; }
    __syncthreads();
    if (tid == 0) {
        unsigned int tot = s_part[0] + s_part[1] + s_part[2] + s_part[3];
        unsigned int mga = s_min[0];
        if (s_min[1] < mga) mga = s_min[1];
        if (s_min[2] < mga) mga = s_min[2];
        if (s_min[3] < mga) mga = s_min[3];
        unsigned int vhi = (tot >= (unsigned int)(k + 2)) ? vk : mga;
        float flo = fromkey(vk), fhi = fromkey(vhi);
        ws[slot] = flo + frac * (fhi - flo);
    }
}

// ---------------- final combine ----------------
__global__ __launch_bounds__(256) void hs_final_kernel(const float* __restrict__ fouts,
                                                       const float* __restrict__ ws,
                                                       float* __restrict__ out) {
    __shared__ float red[256];
    __shared__ float s_feas;
    const int tid = threadIdx.x;
    float fs = 0.f, ps = 0.f;
    for (int t = tid; t < 1024; t += 256) {
        fs += ws[WS_FEAS + t];
        ps += ws[WS_PSIP + t];
    }
    red[tid] = fs;
    __syncthreads();
    for (int s = 128; s > 0; s >>= 1) {
        if (tid < s) red[tid] += red[tid + s];
        __syncthreads();
    }
    if (tid == 0) s_feas = red[0];
    __syncthreads();
    red[tid] = ps;
    __syncthreads();
    for (int s = 128; s > 0; s >>= 1) {
        if (tid < s) red[tid] += red[tid + s];
        __syncthreads();
    }
    if (tid == 0) {
        float psi_sum = red[0];
        float rsum = ws[WS_RSUM + 0] + ws[WS_RSUM + 1] + ws[WS_RSUM + 2] + ws[WS_RSUM + 3];
        float loss = 0.f;
        // radius loss
        float sacc = 0.f;
        for (int q = 0; q < 7; ++q) { float d = ws[QZF + q] - ws[QZR + q]; sacc += d * d; }
        loss += sacc / 7.f;
        // physical feasibility: (ordered_sum/2) / (N * sum|r|)
        loss += (0.5f * s_feas) / ((float)N_PTS * rsum);
        // gan loss
        float g = 0.f;
        for (int b = 0; b < B_SZ; ++b) {
            float p = fouts[b];
            g += 0.9f * fmaxf(logf(p), -100.f) + 0.1f * fmaxf(logf(1.f - p), -100.f);
        }
        loss += -g / (float)B_SZ;
        // grid density loss
        float sx = 0.f, sy = 0.f;
        for (int q = 0; q < 5; ++q) {
            float dx = ws[QXF + q] - ws[QXR + q]; sx += dx * dx;
            float dy = ws[QYF + q] - ws[QYR + q]; sy += dy * dy;
        }
        loss += 0.5f * (sx / 5.f + sy / 5.f);
        // distance loss
        float sd = 0.f;
        for (int t = 0; t < 12; ++t) { float d = ws[QDF + t] - ws[QDR + t]; sd += d * d; }
        loss += sd / 12.f;
        // grid order loss
        loss += -psi_sum / (float)(B_SZ * N_PTS);
        out[0] = loss;
    }
}

extern "C" void kernel_launch(void* const* d_in, const int* in_sizes, int n_in,
                              void* d_out, int out_size, void* d_ws, size_t ws_size,
                              hipStream_t stream) {
    (void)in_sizes; (void)n_in; (void)out_size; (void)ws_size;
    const float* real  = (const float*)d_in[0];
    const float* fake  = (const float*)d_in[1];
    const float* fouts = (const float*)d_in[2];
    float* out = (float*)d_out;
    float* ws  = (float*)d_ws;

    hipLaunchKernelGGL(hs_pair_kernel,   dim3(1536), dim3(256), 0, stream, real, fake, ws);
    hipLaunchKernelGGL(hs_select_kernel, dim3(58),   dim3(256), 0, stream, real, fake, ws);
    hipLaunchKernelGGL(hs_final_kernel,  dim3(1),    dim3(256), 0, stream, fouts, ws, out);
}